// Round 10
// baseline (113.448 us; speedup 1.0000x reference)
//
#include <hip/hip_runtime.h>
#include <math.h>

#define Bb 2
#define Nn 2048
#define Hh 256
#define NH 8
#define HD 32
#define NEDGE 65536
#define LN_EPS 1e-5f
#define MW 64          // mask words per row = N/32
#define LDA2 72
#define ALD 264        // As row stride (bf16)
#define NBW 2112       // nbr row stride (worst-case 2048 + sentinel, padded)

typedef __bf16 bf16_t;
typedef bf16_t bf16x8 __attribute__((ext_vector_type(8)));
typedef bf16_t bf16x4 __attribute__((ext_vector_type(4)));
typedef float f32x4 __attribute__((ext_vector_type(4)));

// ===========================================================================
// K0: QKV GEMM (units 0..767) + edge scatter into pre-zeroed mask (768..1023).
// Round-6 best-measured configuration, verbatim. Mask zeroed by the
// hipMemsetAsync dispatch before this kernel (stream-ordered).
// ===========================================================================
__global__ __launch_bounds__(256) void prep_kernel(
    const float* __restrict__ x,
    const float* __restrict__ Wq, const float* __restrict__ Wk, const float* __restrict__ Wv,
    const int* __restrict__ ei,
    float* __restrict__ Qb, bf16_t* __restrict__ Kb16, bf16_t* __restrict__ Vb16,
    unsigned int* __restrict__ mask)
{
    __shared__ bf16_t As[64 * LDA2];
    __shared__ bf16_t Ws[64 * LDA2];
    const int u = blockIdx.x;
    const int t = threadIdx.x;

    if (u >= 768) {
        // ---- one chunk of 256 edges -> atomicOr into (pre-zeroed) mask ----
        int e = (u - 768) * 256 + t;
        int src = ei[e];
        int dst = ei[NEDGE + e];
        atomicOr(&mask[src * MW + (dst >> 5)], 1u << (dst & 31));
        return;
    }

    // ---- one 64x64 QKV GEMM tile (bf16 MFMA, 4 waves 2x2) ----
    const int lane = t & 63, w = t >> 6;
    const int wm = w & 1, wn = w >> 1;
    const int ml = lane & 15, quad = lane >> 4;
    const int m0 = (u & 63) << 6;
    const int ysel = u >> 6;
    const int wsel = ysel >> 2;
    const float* W = (wsel == 0) ? Wq : ((wsel == 1) ? Wk : Wv);
    const int n0 = (ysel & 3) << 6;
    const int srow = t >> 3, scol = (t & 7) * 8;
    f32x4 acc[2][2];
    f32x4 zero = {0.f, 0.f, 0.f, 0.f};
    acc[0][0] = zero; acc[0][1] = zero; acc[1][0] = zero; acc[1][1] = zero;

    for (int k0 = 0; k0 < Hh; k0 += 64) {
        float4 a[2][2], bwt[2][2];
        #pragma unroll
        for (int s = 0; s < 2; ++s) {
            const float* ap = x + (size_t)(m0 + srow + s * 32) * Hh + k0 + scol;
            a[s][0] = *(const float4*)ap;
            a[s][1] = *(const float4*)(ap + 4);
            const float* bp = W + (size_t)(n0 + srow + s * 32) * Hh + k0 + scol;
            bwt[s][0] = *(const float4*)bp;
            bwt[s][1] = *(const float4*)(bp + 4);
        }
        __syncthreads();
        #pragma unroll
        for (int s = 0; s < 2; ++s) {
            bf16x8 av = {(bf16_t)a[s][0].x, (bf16_t)a[s][0].y, (bf16_t)a[s][0].z, (bf16_t)a[s][0].w,
                         (bf16_t)a[s][1].x, (bf16_t)a[s][1].y, (bf16_t)a[s][1].z, (bf16_t)a[s][1].w};
            bf16x8 bv = {(bf16_t)bwt[s][0].x, (bf16_t)bwt[s][0].y, (bf16_t)bwt[s][0].z, (bf16_t)bwt[s][0].w,
                         (bf16_t)bwt[s][1].x, (bf16_t)bwt[s][1].y, (bf16_t)bwt[s][1].z, (bf16_t)bwt[s][1].w};
            *(bf16x8*)&As[(srow + s * 32) * LDA2 + scol] = av;
            *(bf16x8*)&Ws[(srow + s * 32) * LDA2 + scol] = bv;
        }
        __syncthreads();
        #pragma unroll
        for (int kk = 0; kk < 64; kk += 32) {
            bf16x8 af[2], bfr[2];
            #pragma unroll
            for (int i = 0; i < 2; ++i) {
                af[i]  = *(const bf16x8*)&As[(wm * 32 + i * 16 + ml) * LDA2 + kk + quad * 8];
                bfr[i] = *(const bf16x8*)&Ws[(wn * 32 + i * 16 + ml) * LDA2 + kk + quad * 8];
            }
            #pragma unroll
            for (int i = 0; i < 2; ++i)
                #pragma unroll
                for (int j = 0; j < 2; ++j)
                    acc[i][j] = __builtin_amdgcn_mfma_f32_16x16x32_bf16(af[i], bfr[j], acc[i][j], 0, 0, 0);
        }
    }
    bf16_t* Ob16 = (wsel == 1) ? Kb16 : Vb16;
    #pragma unroll
    for (int i = 0; i < 2; ++i)
        #pragma unroll
        for (int j = 0; j < 2; ++j)
            #pragma unroll
            for (int r = 0; r < 4; ++r) {
                int mg = m0 + wm * 32 + i * 16 + quad * 4 + r;
                int ng = n0 + wn * 32 + j * 16 + ml;
                float v = acc[i][j][r];
                if (wsel == 0) Qb[(size_t)mg * Hh + ng] = v;
                else           Ob16[(size_t)mg * Hh + ng] = (bf16_t)v;
            }
}

// ===========================================================================
// K1: fused attention + out-projection + residual + LayerNorm.
// Round-6 attention structure (16 waves, wave-per-row, barrier-free neighbor
// loop) with a barrier-light epilogue: B-fragments loaded DIRECTLY from fp32
// Wo (in-register bf16 cvt; same values, same RNE cast, same ascending
// k-order as the staged version -> bit-identical output). Removes 8 of the
// 10 epilogue barriers AND drops LDS 112.9 KB -> 74.3 KB, so 2 blocks/CU are
// co-resident through the attention phase as well.
// ===========================================================================
__global__ __launch_bounds__(1024) void attn_out_ln_kernel(
    const float* __restrict__ Qb, const bf16_t* __restrict__ Kb16, const bf16_t* __restrict__ Vb16,
    const unsigned int* __restrict__ mask, const float* __restrict__ Wo,
    const float* __restrict__ x, const float* __restrict__ gamma, const float* __restrict__ beta,
    float* __restrict__ out)
{
    __shared__ __align__(16) char smem[16 * NBW * 2 + 16 * ALD * 2];   // 74.3 KB
    unsigned short* nbr = (unsigned short*)smem;              // [16][NBW]
    float*  ybuf = (float*)smem;                              // [16][260], alias over nbr
    bf16_t* As   = (bf16_t*)(smem + 16 * NBW * 2);            // [16][ALD]

    const int t = threadIdx.x;
    const int w = t >> 6, lane = t & 63;
    const int ml = lane & 15, quad = lane >> 4;
    const int g = (blockIdx.x << 4) + w;     // global row 0..4095
    const int i = g & (Nn - 1);
    const int b = g >> 11;

    // ---- decode mask row i into this wave's neighbor list ----
    unsigned int bits = mask[i * MW + lane];
    int cnt = __popc(bits);
    int incl = cnt;
    #pragma unroll
    for (int off = 1; off < 64; off <<= 1) {
        int v = __shfl_up(incl, off, 64);
        if (lane >= off) incl += v;
    }
    int idx = incl - cnt;
    unsigned int bb = bits;
    while (bb) {
        int bit = __ffs(bb) - 1;
        nbr[w * NBW + idx++] = (unsigned short)(lane * 32 + bit);
        bb &= bb - 1;
    }
    int nn = __shfl(incl, 63, 64);
    if (lane == 63) nbr[w * NBW + idx] = 0;   // sentinel keeps prefetch addr valid
    __syncthreads();

    // ---- in-register online-softmax attention (round-6 loop, verbatim) ----
    const int off4 = lane << 2;
    const float4 qv = *(const float4*)(Qb + (size_t)g * Hh + off4);
    const bf16_t* kb = Kb16 + ((size_t)b << 19);   // b * 2048 * 256
    const bf16_t* vb = Vb16 + ((size_t)b << 19);
    const float scale = 0.17677669529663687f;      // 1/sqrt(32)

    float m_run = -1e30f, l_run = 0.f;
    float o0 = 0.f, o1 = 0.f, o2 = 0.f, o3 = 0.f;
    if (nn > 0) {
        int j = nbr[w * NBW];
        bf16x4 kv = *(const bf16x4*)(kb + ((size_t)j << 8) + off4);
        bf16x4 vv = *(const bf16x4*)(vb + ((size_t)j << 8) + off4);
        for (int n = 0; n < nn; ++n) {
            int jn = nbr[w * NBW + n + 1];    // sentinel makes this always valid
            bf16x4 kn = *(const bf16x4*)(kb + ((size_t)jn << 8) + off4);
            bf16x4 vn = *(const bf16x4*)(vb + ((size_t)jn << 8) + off4);
            float p = fmaf((float)kv.x, qv.x, fmaf((float)kv.y, qv.y,
                      fmaf((float)kv.z, qv.z, (float)kv.w * qv.w)));
            p += __shfl_xor(p, 1, 64);
            p += __shfl_xor(p, 2, 64);
            p += __shfl_xor(p, 4, 64);   // 8-lane head group holds head dot
            p *= scale;
            float m_new = fmaxf(m_run, p);
            float alpha = __expf(m_run - m_new);
            float wgt   = __expf(p - m_new);
            l_run = fmaf(l_run, alpha, wgt);
            o0 = fmaf(o0, alpha, wgt * (float)vv.x);
            o1 = fmaf(o1, alpha, wgt * (float)vv.y);
            o2 = fmaf(o2, alpha, wgt * (float)vv.z);
            o3 = fmaf(o3, alpha, wgt * (float)vv.w);
            m_run = m_new;
            kv = kn; vv = vn;
        }
    }
    float linv = (l_run > 0.f) ? 1.f / l_run : 0.f;
    bf16x4 arow = {(bf16_t)(o0 * linv), (bf16_t)(o1 * linv),
                   (bf16_t)(o2 * linv), (bf16_t)(o3 * linv)};
    *(bf16x4*)&As[w * ALD + off4] = arow;
    __syncthreads();   // all 16 A-rows written; all nbr reads complete

    // ---- out-projection: C[16 x 256] = A @ Wo^T; wave w -> cols w*16..w*16+15.
    // B-fragment rows (w*16+ml) read straight from fp32 Wo, bf16 cvt in-reg.
    // k ascending in 32-steps (k8*32), identical chain to the staged version.
    f32x4 acc = {0.f, 0.f, 0.f, 0.f};
    #pragma unroll
    for (int k8 = 0; k8 < 8; ++k8) {
        bf16x8 af = *(const bf16x8*)&As[ml * ALD + (k8 << 5) + (quad << 3)];
        const float* wp = Wo + (size_t)((w << 4) + ml) * Hh + (k8 << 5) + (quad << 3);
        float4 w0 = ((const float4*)wp)[0];
        float4 w1 = ((const float4*)wp)[1];
        bf16x8 bfr = {(bf16_t)w0.x, (bf16_t)w0.y, (bf16_t)w0.z, (bf16_t)w0.w,
                      (bf16_t)w1.x, (bf16_t)w1.y, (bf16_t)w1.z, (bf16_t)w1.w};
        acc = __builtin_amdgcn_mfma_f32_16x16x32_bf16(af, bfr, acc, 0, 0, 0);
    }
    // ---- y = C + x (residual) into ybuf (aliases nbr; attention fully done) ----
    #pragma unroll
    for (int r = 0; r < 4; ++r) {
        int row = quad * 4 + r;
        int col = (w << 4) + ml;
        ybuf[row * 260 + col] = acc[r] + x[(size_t)((blockIdx.x << 4) + row) * Hh + col];
    }
    __syncthreads();
    // ---- LayerNorm: wave w handles row w ----
    {
        float4 v = *(const float4*)&ybuf[w * 260 + off4];
        float sum = v.x + v.y + v.z + v.w;
        #pragma unroll
        for (int m = 1; m < 64; m <<= 1) sum += __shfl_xor(sum, m, 64);
        float mu = sum * (1.f / Hh);
        float4 d = {v.x - mu, v.y - mu, v.z - mu, v.w - mu};
        float ss = d.x * d.x + d.y * d.y + d.z * d.z + d.w * d.w;
        #pragma unroll
        for (int m = 1; m < 64; m <<= 1) ss += __shfl_xor(ss, m, 64);
        float r = rsqrtf(ss * (1.f / Hh) + LN_EPS);
        float4 gm = *(const float4*)(gamma + off4);
        float4 bt = *(const float4*)(beta + off4);
        float4 ov = {d.x * r * gm.x + bt.x, d.y * r * gm.y + bt.y,
                     d.z * r * gm.z + bt.z, d.w * r * gm.w + bt.w};
        *(float4*)(out + (size_t)g * Hh + off4) = ov;
    }
}

extern "C" void kernel_launch(void* const* d_in, const int* in_sizes, int n_in,
                              void* d_out, int out_size, void* d_ws, size_t ws_size,
                              hipStream_t stream) {
    const float* x     = (const float*)d_in[0];
    const int*   ei    = (const int*)d_in[1];
    // d_in[2] = edge_weights: unused by the reference
    const float* Wq    = (const float*)d_in[3];
    const float* Wk    = (const float*)d_in[4];
    const float* Wv    = (const float*)d_in[5];
    const float* Wo    = (const float*)d_in[6];
    const float* gamma = (const float*)d_in[7];
    const float* beta  = (const float*)d_in[8];
    float* out = (float*)d_out;

    const int NTOK = Bb * Nn * Hh;  // 1048576
    float*  Qb    = (float*)d_ws;
    bf16_t* Kb16  = (bf16_t*)(Qb + NTOK);
    bf16_t* Vb16  = Kb16 + NTOK;
    unsigned int* mask = (unsigned int*)(Vb16 + NTOK);

    hipMemsetAsync(mask, 0, Nn * MW * sizeof(unsigned int), stream);
    hipLaunchKernelGGL(prep_kernel, dim3(1024), dim3(256), 0, stream,
                       x, Wq, Wk, Wv, ei, Qb, Kb16, Vb16, mask);
    hipLaunchKernelGGL(attn_out_ln_kernel, dim3((Bb * Nn) / 16), dim3(1024), 0, stream,
                       Qb, Kb16, Vb16, mask, Wo, x, gamma, beta, out);
}

// Round 12
// 110.701 us; speedup vs baseline: 1.0248x; 1.0248x over previous
//
#include <hip/hip_runtime.h>
#include <math.h>

#define Bb 2
#define Nn 2048
#define Hh 256
#define NH 8
#define HD 32
#define NEDGE 65536
#define LN_EPS 1e-5f
#define MW 64          // mask words per row = N/32
#define LDA2 72
#define ALD 264        // As row stride (bf16)
#define NBW 2112       // nbr row stride (worst-case 2048 + sentinel, padded)

typedef __bf16 bf16_t;
typedef bf16_t bf16x8 __attribute__((ext_vector_type(8)));
typedef bf16_t bf16x4 __attribute__((ext_vector_type(4)));
typedef float f32x4 __attribute__((ext_vector_type(4)));

// ===========================================================================
// K0: QKV GEMM (units 0..767) + build mask from edges (units 768..1023).
// Mask zeroed by hipMemsetAsync before this kernel (stream-ordered).
// Round-6 best-measured configuration (110.0 us), verbatim.
// ===========================================================================
__global__ __launch_bounds__(256) void prep_kernel(
    const float* __restrict__ x,
    const float* __restrict__ Wq, const float* __restrict__ Wk, const float* __restrict__ Wv,
    const int* __restrict__ ei,
    float* __restrict__ Qb, bf16_t* __restrict__ Kb16, bf16_t* __restrict__ Vb16,
    unsigned int* __restrict__ mask)
{
    __shared__ bf16_t As[64 * LDA2];
    __shared__ bf16_t Ws[64 * LDA2];
    const int u = blockIdx.x;
    const int t = threadIdx.x;

    if (u >= 768) {
        int e = (u - 768) * 256 + t;
        int src = ei[e];
        int dst = ei[NEDGE + e];
        atomicOr(&mask[src * MW + (dst >> 5)], 1u << (dst & 31));
        return;
    }

    const int lane = t & 63, w = t >> 6;
    const int wm = w & 1, wn = w >> 1;
    const int ml = lane & 15, quad = lane >> 4;
    const int m0 = (u & 63) << 6;
    const int ysel = u >> 6;
    const int wsel = ysel >> 2;
    const float* W = (wsel == 0) ? Wq : ((wsel == 1) ? Wk : Wv);
    const int n0 = (ysel & 3) << 6;
    const int srow = t >> 3, scol = (t & 7) * 8;
    f32x4 acc[2][2];
    f32x4 zero = {0.f, 0.f, 0.f, 0.f};
    acc[0][0] = zero; acc[0][1] = zero; acc[1][0] = zero; acc[1][1] = zero;

    for (int k0 = 0; k0 < Hh; k0 += 64) {
        float4 a[2][2], bwt[2][2];
        #pragma unroll
        for (int s = 0; s < 2; ++s) {
            const float* ap = x + (size_t)(m0 + srow + s * 32) * Hh + k0 + scol;
            a[s][0] = *(const float4*)ap;
            a[s][1] = *(const float4*)(ap + 4);
            const float* bp = W + (size_t)(n0 + srow + s * 32) * Hh + k0 + scol;
            bwt[s][0] = *(const float4*)bp;
            bwt[s][1] = *(const float4*)(bp + 4);
        }
        __syncthreads();
        #pragma unroll
        for (int s = 0; s < 2; ++s) {
            bf16x8 av = {(bf16_t)a[s][0].x, (bf16_t)a[s][0].y, (bf16_t)a[s][0].z, (bf16_t)a[s][0].w,
                         (bf16_t)a[s][1].x, (bf16_t)a[s][1].y, (bf16_t)a[s][1].z, (bf16_t)a[s][1].w};
            bf16x8 bv = {(bf16_t)bwt[s][0].x, (bf16_t)bwt[s][0].y, (bf16_t)bwt[s][0].z, (bf16_t)bwt[s][0].w,
                         (bf16_t)bwt[s][1].x, (bf16_t)bwt[s][1].y, (bf16_t)bwt[s][1].z, (bf16_t)bwt[s][1].w};
            *(bf16x8*)&As[(srow + s * 32) * LDA2 + scol] = av;
            *(bf16x8*)&Ws[(srow + s * 32) * LDA2 + scol] = bv;
        }
        __syncthreads();
        #pragma unroll
        for (int kk = 0; kk < 64; kk += 32) {
            bf16x8 af[2], bfr[2];
            #pragma unroll
            for (int i = 0; i < 2; ++i) {
                af[i]  = *(const bf16x8*)&As[(wm * 32 + i * 16 + ml) * LDA2 + kk + quad * 8];
                bfr[i] = *(const bf16x8*)&Ws[(wn * 32 + i * 16 + ml) * LDA2 + kk + quad * 8];
            }
            #pragma unroll
            for (int i = 0; i < 2; ++i)
                #pragma unroll
                for (int j = 0; j < 2; ++j)
                    acc[i][j] = __builtin_amdgcn_mfma_f32_16x16x32_bf16(af[i], bfr[j], acc[i][j], 0, 0, 0);
        }
    }
    bf16_t* Ob16 = (wsel == 1) ? Kb16 : Vb16;
    #pragma unroll
    for (int i = 0; i < 2; ++i)
        #pragma unroll
        for (int j = 0; j < 2; ++j)
            #pragma unroll
            for (int r = 0; r < 4; ++r) {
                int mg = m0 + wm * 32 + i * 16 + quad * 4 + r;
                int ng = n0 + wn * 32 + j * 16 + ml;
                float v = acc[i][j][r];
                if (wsel == 0) Qb[(size_t)mg * Hh + ng] = v;
                else           Ob16[(size_t)mg * Hh + ng] = (bf16_t)v;
            }
}

// ===========================================================================
// K1: fused attention + out-projection + residual + LayerNorm (round-6 best,
// verbatim). Block = 1024 threads = 16 waves; wave w owns global row
// g = bid*16 + w and runs the in-register online-softmax loop (no barriers in
// the neighbor loop). The 16 finished rows form a full M=16 bf16 A-tile in
// LDS; epilogue = proven out_ln GEMM (wave w computes cols w*16..w*16+15,
// 8 MFMA, Ws-staged), then residual + LN (wave w = row w).
// LDS: nbr[16][2112] (67.6 KB, aliased by ybuf later) + As 8.4 KB +
// Ws 36.9 KB = 112.9 KB -> 1 block/CU, 16 waves.
// ===========================================================================
__global__ __launch_bounds__(1024) void attn_out_ln_kernel(
    const float* __restrict__ Qb, const bf16_t* __restrict__ Kb16, const bf16_t* __restrict__ Vb16,
    const unsigned int* __restrict__ mask, const float* __restrict__ Wo,
    const float* __restrict__ x, const float* __restrict__ gamma, const float* __restrict__ beta,
    float* __restrict__ out)
{
    __shared__ __align__(16) char smem[16 * NBW * 2 + 16 * ALD * 2 + 256 * LDA2 * 2];
    unsigned short* nbr = (unsigned short*)smem;              // [16][NBW]
    float*  ybuf = (float*)smem;                              // [16][260], alias over nbr
    bf16_t* As   = (bf16_t*)(smem + 16 * NBW * 2);            // [16][ALD]
    bf16_t* Ws   = (bf16_t*)(smem + 16 * NBW * 2 + 16 * ALD * 2);  // [256][LDA2]

    const int t = threadIdx.x;
    const int w = t >> 6, lane = t & 63;
    const int ml = lane & 15, quad = lane >> 4;
    const int g = (blockIdx.x << 4) + w;     // global row 0..4095
    const int i = g & (Nn - 1);
    const int b = g >> 11;

    // ---- decode mask row i into this wave's neighbor list ----
    unsigned int bits = mask[i * MW + lane];
    int cnt = __popc(bits);
    int incl = cnt;
    #pragma unroll
    for (int off = 1; off < 64; off <<= 1) {
        int v = __shfl_up(incl, off, 64);
        if (lane >= off) incl += v;
    }
    int idx = incl - cnt;
    unsigned int bb = bits;
    while (bb) {
        int bit = __ffs(bb) - 1;
        nbr[w * NBW + idx++] = (unsigned short)(lane * 32 + bit);
        bb &= bb - 1;
    }
    int nn = __shfl(incl, 63, 64);
    if (lane == 63) nbr[w * NBW + idx] = 0;   // sentinel keeps prefetch addr valid
    __syncthreads();

    // ---- in-register online-softmax attention ----
    const int off4 = lane << 2;
    const float4 qv = *(const float4*)(Qb + (size_t)g * Hh + off4);
    const bf16_t* kb = Kb16 + ((size_t)b << 19);   // b * 2048 * 256
    const bf16_t* vb = Vb16 + ((size_t)b << 19);
    const float scale = 0.17677669529663687f;      // 1/sqrt(32)

    float m_run = -1e30f, l_run = 0.f;
    float o0 = 0.f, o1 = 0.f, o2 = 0.f, o3 = 0.f;
    if (nn > 0) {
        int j = nbr[w * NBW];
        bf16x4 kv = *(const bf16x4*)(kb + ((size_t)j << 8) + off4);
        bf16x4 vv = *(const bf16x4*)(vb + ((size_t)j << 8) + off4);
        for (int n = 0; n < nn; ++n) {
            int jn = nbr[w * NBW + n + 1];    // sentinel makes this always valid
            bf16x4 kn = *(const bf16x4*)(kb + ((size_t)jn << 8) + off4);
            bf16x4 vn = *(const bf16x4*)(vb + ((size_t)jn << 8) + off4);
            float p = fmaf((float)kv.x, qv.x, fmaf((float)kv.y, qv.y,
                      fmaf((float)kv.z, qv.z, (float)kv.w * qv.w)));
            p += __shfl_xor(p, 1, 64);
            p += __shfl_xor(p, 2, 64);
            p += __shfl_xor(p, 4, 64);   // 8-lane head group holds head dot
            p *= scale;
            float m_new = fmaxf(m_run, p);
            float alpha = __expf(m_run - m_new);
            float wgt   = __expf(p - m_new);
            l_run = fmaf(l_run, alpha, wgt);
            o0 = fmaf(o0, alpha, wgt * (float)vv.x);
            o1 = fmaf(o1, alpha, wgt * (float)vv.y);
            o2 = fmaf(o2, alpha, wgt * (float)vv.z);
            o3 = fmaf(o3, alpha, wgt * (float)vv.w);
            m_run = m_new;
            kv = kn; vv = vn;
        }
    }
    float linv = (l_run > 0.f) ? 1.f / l_run : 0.f;
    bf16x4 arow = {(bf16_t)(o0 * linv), (bf16_t)(o1 * linv),
                   (bf16_t)(o2 * linv), (bf16_t)(o3 * linv)};
    *(bf16x4*)&As[w * ALD + off4] = arow;
    __syncthreads();   // all 16 A-rows + all nbr reads complete

    // ---- out-projection: C[16 x 256] = A[16 x 256] @ Wo^T, wave w -> cols w*16.. ----
    const int wrow = t >> 2, wcol = (t & 3) << 4;   // Ws staging: row 0..255, 16 cols
    f32x4 acc = {0.f, 0.f, 0.f, 0.f};
    for (int k0 = 0; k0 < Hh; k0 += 64) {
        const float* wp = Wo + (size_t)wrow * Hh + k0 + wcol;
        float4 w0 = ((const float4*)wp)[0];
        float4 w1 = ((const float4*)wp)[1];
        float4 w2 = ((const float4*)wp)[2];
        float4 w3 = ((const float4*)wp)[3];
        __syncthreads();   // previous iteration's MFMA reads of Ws done
        bf16x8 lo = {(bf16_t)w0.x, (bf16_t)w0.y, (bf16_t)w0.z, (bf16_t)w0.w,
                     (bf16_t)w1.x, (bf16_t)w1.y, (bf16_t)w1.z, (bf16_t)w1.w};
        bf16x8 hi = {(bf16_t)w2.x, (bf16_t)w2.y, (bf16_t)w2.z, (bf16_t)w2.w,
                     (bf16_t)w3.x, (bf16_t)w3.y, (bf16_t)w3.z, (bf16_t)w3.w};
        *(bf16x8*)&Ws[wrow * LDA2 + wcol] = lo;
        *(bf16x8*)&Ws[wrow * LDA2 + wcol + 8] = hi;
        __syncthreads();
        #pragma unroll
        for (int kk = 0; kk < 64; kk += 32) {
            bf16x8 af  = *(const bf16x8*)&As[ml * ALD + k0 + kk + quad * 8];
            bf16x8 bfr = *(const bf16x8*)&Ws[(w * 16 + ml) * LDA2 + kk + quad * 8];
            acc = __builtin_amdgcn_mfma_f32_16x16x32_bf16(af, bfr, acc, 0, 0, 0);
        }
    }
    // ---- y = C + x (residual) into ybuf (aliases nbr; attention fully done) ----
    #pragma unroll
    for (int r = 0; r < 4; ++r) {
        int row = quad * 4 + r;
        int col = (w << 4) + ml;
        ybuf[row * 260 + col] = acc[r] + x[(size_t)((blockIdx.x << 4) + row) * Hh + col];
    }
    __syncthreads();
    // ---- LayerNorm: wave w handles row w ----
    {
        float4 v = *(const float4*)&ybuf[w * 260 + off4];
        float sum = v.x + v.y + v.z + v.w;
        #pragma unroll
        for (int m = 1; m < 64; m <<= 1) sum += __shfl_xor(sum, m, 64);
        float mu = sum * (1.f / Hh);
        float4 d = {v.x - mu, v.y - mu, v.z - mu, v.w - mu};
        float ss = d.x * d.x + d.y * d.y + d.z * d.z + d.w * d.w;
        #pragma unroll
        for (int m = 1; m < 64; m <<= 1) ss += __shfl_xor(ss, m, 64);
        float r = rsqrtf(ss * (1.f / Hh) + LN_EPS);
        float4 gm = *(const float4*)(gamma + off4);
        float4 bt = *(const float4*)(beta + off4);
        float4 ov = {d.x * r * gm.x + bt.x, d.y * r * gm.y + bt.y,
                     d.z * r * gm.z + bt.z, d.w * r * gm.w + bt.w};
        *(float4*)(out + (size_t)g * Hh + off4) = ov;
    }
}

extern "C" void kernel_launch(void* const* d_in, const int* in_sizes, int n_in,
                              void* d_out, int out_size, void* d_ws, size_t ws_size,
                              hipStream_t stream) {
    const float* x     = (const float*)d_in[0];
    const int*   ei    = (const int*)d_in[1];
    // d_in[2] = edge_weights: unused by the reference
    const float* Wq    = (const float*)d_in[3];
    const float* Wk    = (const float*)d_in[4];
    const float* Wv    = (const float*)d_in[5];
    const float* Wo    = (const float*)d_in[6];
    const float* gamma = (const float*)d_in[7];
    const float* beta  = (const float*)d_in[8];
    float* out = (float*)d_out;

    const int NTOK = Bb * Nn * Hh;  // 1048576
    float*  Qb    = (float*)d_ws;
    bf16_t* Kb16  = (bf16_t*)(Qb + NTOK);
    bf16_t* Vb16  = Kb16 + NTOK;
    unsigned int* mask = (unsigned int*)(Vb16 + NTOK);

    hipMemsetAsync(mask, 0, Nn * MW * sizeof(unsigned int), stream);
    hipLaunchKernelGGL(prep_kernel, dim3(1024), dim3(256), 0, stream,
                       x, Wq, Wk, Wv, ei, Qb, Kb16, Vb16, mask);
    hipLaunchKernelGGL(attn_out_ln_kernel, dim3((Bb * Nn) / 16), dim3(1024), 0, stream,
                       Qb, Kb16, Vb16, mask, Wo, x, gamma, beta, out);
}